// Round 1
// 654.392 us; speedup vs baseline: 1.1191x; 1.1191x over previous
//
#include <hip/hip_runtime.h>
#include <math.h>

#define HW 262144
#define C_ 256
#define SAMPLE_NUM_ 4096
#define TAU_ 0.07f
#define RTAU_ (1.0f/0.07f)
#define THRESH_ 0.8f
#define NCHUNK_MAX 41
#define NPB 512              // k_core partial blocks

typedef _Float16 half_t;
typedef __attribute__((ext_vector_type(4))) _Float16 half4;
typedef __attribute__((ext_vector_type(8))) _Float16 half8;
typedef __attribute__((ext_vector_type(4))) float f32x4;

// ---- ws byte offsets ----
#define OFF_GSUM   0          // double
#define OFF_BSUM   8          // double
#define OFF_CNTS   16         // int[4]: gcnt,bcnt,gcoreCnt,bcoreCnt
#define OFF_MGC    64         // double[2]: mgc, mbc
#define OFF_PLANI  96         // int[16]
#define OFF_CORESUMG 256      // float[256]
#define OFF_CORESUMB 1280     // float[256] (contiguous after CORESUMG)
#define OFF_CHUNKSUM 2304     // float[82]
#define OFF_COREMEANG 2688    // float[256]
#define OFF_COREMEANB 3712    // float[256]
#define OFF_NPOS   4736       // float[2]
#define ZERO_BYTES 16384
#define OFF_RNORM  16384                        // float[262144]
#define OFF_CNTPOOL (OFF_RNORM + 262144*4)      // int[4][4096]
#define OFF_OFFPOOL (OFF_CNTPOOL + 4*4096*4)    // int[4][4096]
#define OFF_TOTALS  (OFF_OFFPOOL + 4*4096*4)    // int[4] (+pad)
#define OFF_APIX    (OFF_TOTALS + 64)           // int[8192]
#define OFF_NA      (OFF_APIX + 8192*4)         // float[8192]
#define OFF_PLOG    (OFF_NA + 8192*4)           // float[8192]
#define OFF_RNA     (OFF_PLOG + 8192*4)         // float[8192]
#define OFF_FEATSH  (OFF_RNA + 8192*4)          // half[8192*256]  (4 MB, 16B-aligned)
#define OFF_PART    (OFF_FEATSH + 8192*256*2)   // float[512][NPB] (1 MB)

__device__ __forceinline__ float waveReduceSum(float v){
    for(int off=32; off; off>>=1) v += __shfl_down(v, off, 64);
    return v;
}
__device__ __forceinline__ int waveReduceSumI(int v){
    for(int off=32; off; off>>=1) v += __shfl_down(v, off, 64);
    return v;
}

// async global->LDS DMA, 16B per lane; LDS dest = wave-uniform base + lane*16
typedef __attribute__((address_space(1))) void as1_void;
typedef __attribute__((address_space(3))) void as3_void;
__device__ __forceinline__ void gl_lds16(const void* g, void* l){
    __builtin_amdgcn_global_load_lds((as1_void*)g, (as3_void*)l, 16, 0, 0);
}

// K1: confidence sums/counts + core counts (block-reduced, 1 atomic set per block)
__global__ void k_conf(const float* __restrict__ logits, const int* __restrict__ seg, void* ws){
    int tid = blockIdx.x*blockDim.x + threadIdx.x;
    int stride = gridDim.x*blockDim.x;
    float gs=0.f, bs=0.f; int gc=0, bc=0, gcc=0, bcc=0;
    for(int p=tid; p<HW; p+=stride){
        int s = seg[p];
        float l0 = logits[p], l1 = logits[HW+p];
        if(s==1){ gs += l1; gc++; if(l1 >= THRESH_) gcc++; }
        else    { bs += l0; bc++; if(l0 >= THRESH_) bcc++; }
    }
    gs = waveReduceSum(gs); bs = waveReduceSum(bs);
    gc = waveReduceSumI(gc); bc = waveReduceSumI(bc);
    gcc = waveReduceSumI(gcc); bcc = waveReduceSumI(bcc);
    __shared__ float rf[8];
    __shared__ int   ri[16];
    int lane = threadIdx.x & 63, wid = threadIdx.x >> 6;
    if(lane==0){
        rf[wid]=gs; rf[4+wid]=bs;
        ri[wid]=gc; ri[4+wid]=bc; ri[8+wid]=gcc; ri[12+wid]=bcc;
    }
    __syncthreads();
    if(threadIdx.x==0){
        float G=rf[0]+rf[1]+rf[2]+rf[3], B=rf[4]+rf[5]+rf[6]+rf[7];
        int GC=ri[0]+ri[1]+ri[2]+ri[3], BC=ri[4]+ri[5]+ri[6]+ri[7];
        int GCC=ri[8]+ri[9]+ri[10]+ri[11], BCC=ri[12]+ri[13]+ri[14]+ri[15];
        atomicAdd((double*)((char*)ws+OFF_GSUM), (double)G);
        atomicAdd((double*)((char*)ws+OFF_BSUM), (double)B);
        int* c = (int*)((char*)ws+OFF_CNTS);
        atomicAdd(c+0, GC); atomicAdd(c+1, BC);
        atomicAdd(c+2, GCC); atomicAdd(c+3, BCC);
    }
}

// K2: plan part 1
__global__ void k_plan1(void* ws){
    double gs = *(double*)((char*)ws+OFF_GSUM);
    double bs = *(double*)((char*)ws+OFF_BSUM);
    int* cnts = (int*)((char*)ws+OFF_CNTS);
    double mgc = gs / ((double)cnts[0] + 1e-8);
    double mbc = bs / ((double)cnts[1] + 1e-8);
    double* md = (double*)((char*)ws+OFF_MGC);
    md[0]=mgc; md[1]=mbc;
    int* pi = (int*)((char*)ws+OFF_PLANI);
    int eg = (int)(SAMPLE_NUM_*(1.0-mgc)); if(eg<1) eg=1;
    int eb = (int)(SAMPLE_NUM_*(1.0-mbc)); if(eb<1) eb=1;
    pi[0]=eg; pi[1]=SAMPLE_NUM_-eg; pi[2]=eb; pi[3]=SAMPLE_NUM_-eb;
}

// K3: per-pixel reciprocal channel norms; fully coalesced
__global__ void k_norm(const float* __restrict__ x, void* ws){
    int p = blockIdx.x*blockDim.x + threadIdx.x;
    float ss = 0.f;
    #pragma unroll 8
    for(int c=0;c<C_;c++){ float v = x[(size_t)c*HW + p]; ss += v*v; }
    ((float*)((char*)ws+OFF_RNORM))[p] = 1.0f / fmaxf(sqrtf(ss), 1e-12f);
}

// K4: pool counts per 64-pixel thread chunk
__global__ void k_poolcount(const float* __restrict__ logits, const int* __restrict__ seg, void* ws){
    int t = blockIdx.x*blockDim.x + threadIdx.x;  // 4096 threads
    const double* md = (const double*)((char*)ws+OFF_MGC);
    double mgc = md[0], mbc = md[1];
    int cnt[4] = {0,0,0,0};
    int p0 = t*64;
    for(int i=0;i<64;i++){
        int p = p0+i; int s = seg[p]; int q;
        if(s==1) q = ((double)logits[HW+p] >= mgc) ? 0 : 1;
        else     q = ((double)logits[p]    >= mbc) ? 2 : 3;
        cnt[q]++;
    }
    int* cp = (int*)((char*)ws+OFF_CNTPOOL);
    for(int q=0;q<4;q++) cp[q*4096 + t] = cnt[q];
}

// K5: exclusive scan over 4096 thread-chunk counts, one block per pool
__global__ void k_scan(void* ws){
    int q = blockIdx.x, j = threadIdx.x;
    int* cp = (int*)((char*)ws+OFF_CNTPOOL) + q*4096;
    int* op = (int*)((char*)ws+OFF_OFFPOOL) + q*4096;
    __shared__ int s[256];
    int base = j*16, sj=0, loc[16];
    for(int i=0;i<16;i++){ loc[i]=cp[base+i]; sj+=loc[i]; }
    s[j]=sj; __syncthreads();
    for(int off=1; off<256; off<<=1){
        int v = (j>=off)? s[j-off] : 0;
        __syncthreads();
        s[j] += v;
        __syncthreads();
    }
    int ex = s[j]-sj;
    for(int i=0;i<16;i++){ op[base+i]=ex; ex+=loc[i]; }
    if(j==255) ((int*)((char*)ws+OFF_TOTALS))[q] = s[255];
}

// K5b: plan part 2
__global__ void k_plan2(void* ws){
    int* pi = (int*)((char*)ws+OFF_PLANI);
    int* tot = (int*)((char*)ws+OFF_TOTALS);
    int sge = min(tot[0], pi[0]);
    int sgh = min(tot[1], pi[1]);
    int sbe = min(tot[2], pi[2]);
    int sbh = min(tot[3], pi[3]);
    int ng = sge+sgh, nb = sbe+sbh;
    pi[4]=sge; pi[5]=sgh; pi[6]=sbe; pi[7]=sbh;
    pi[8]=ng; pi[9]=nb; pi[10]=ng+nb; pi[11]=nb;
    pi[12]=0; pi[13]=sge; pi[14]=ng; pi[15]=ng+sbe;
}

// K6: deterministic compaction
__global__ void k_fill(const float* __restrict__ logits, const int* __restrict__ seg, void* ws){
    int t = blockIdx.x*blockDim.x + threadIdx.x;
    const double* md = (const double*)((char*)ws+OFF_MGC);
    double mgc = md[0], mbc = md[1];
    int* op = (int*)((char*)ws+OFF_OFFPOOL);
    int* pi = (int*)((char*)ws+OFF_PLANI);
    int* apix = (int*)((char*)ws+OFF_APIX);
    int run[4], sel[4], base[4];
    for(int q=0;q<4;q++){ run[q]=op[q*4096+t]; sel[q]=pi[4+q]; base[q]=pi[12+q]; }
    int p0 = t*64;
    for(int i=0;i<64;i++){
        int p = p0+i; int s = seg[p]; int q;
        if(s==1) q = ((double)logits[HW+p] >= mgc) ? 0 : 1;
        else     q = ((double)logits[p]    >= mbc) ? 2 : 3;
        int r = run[q]++;
        if(r < sel[q]) apix[base[q]+r] = p;
    }
}

// K7: gather + normalize anchor features -> fp16 table. grid (128 a-tiles, 16 ch-groups).
__global__ void k_gather(const float* __restrict__ x, void* ws){
    int* pi = (int*)((char*)ws+OFF_PLANI);
    int ntot = pi[10];
    int a0 = blockIdx.x*64;
    int c0 = blockIdx.y*16;
    int tid = threadIdx.x;
    int lane = tid & 63, wid = tid >> 6;
    __shared__ float T[16][65];
    int a = a0 + lane;
    int p = -1; float rn = 0.f;
    if(a < ntot){
        p = ((int*)((char*)ws+OFF_APIX))[a];
        rn = ((float*)((char*)ws+OFF_RNORM))[p];
    }
    #pragma unroll
    for(int i=0;i<4;i++){
        int c = c0 + wid*4 + i;
        float v = (p>=0) ? x[(size_t)c*HW + p]*rn : 0.0f;
        T[wid*4+i][lane] = v;
    }
    __syncthreads();
    int aL = tid & 63, cq = tid >> 6;
    half4 h;
    h[0] = (half_t)T[cq*4+0][aL]; h[1] = (half_t)T[cq*4+1][aL];
    h[2] = (half_t)T[cq*4+2][aL]; h[3] = (half_t)T[cq*4+3][aL];
    *(half4*)&((half_t*)((char*)ws+OFF_FEATSH))[(size_t)(a0+aL)*C_ + c0 + cq*4] = h;
}

// K8a: per-channel core sums -> per-block partials (no contended atomics)
__global__ void k_core(const float* __restrict__ x, const float* __restrict__ logits,
                       const int* __restrict__ seg, void* ws){
    __shared__ float wg[512], wb[512];
    int p0 = blockIdx.x*512;
    int tid = threadIdx.x;
    const float* rnorm = (const float*)((char*)ws+OFF_RNORM);
    for(int i=tid; i<512; i+=256){
        int p = p0+i; int s = seg[p];
        float rn = rnorm[p];
        wg[i] = (s==1 && logits[HW+p] >= THRESH_) ? rn : 0.0f;
        wb[i] = (s==0 && logits[p]    >= THRESH_) ? rn : 0.0f;
    }
    __syncthreads();
    float* part = (float*)((char*)ws+OFF_PART);
    int lane = tid & 63, wid = tid >> 6;
    for(int c=wid; c<C_; c+=4){
        float gs=0.f, bs=0.f;
        #pragma unroll
        for(int i=0;i<8;i++){
            int idx = i*64 + lane;
            float xv = x[(size_t)c*HW + p0 + idx];
            gs += xv*wg[idx]; bs += xv*wb[idx];
        }
        gs = waveReduceSum(gs); bs = waveReduceSum(bs);
        if(lane==0){
            part[(size_t)c*NPB + blockIdx.x]       = gs;
            part[(size_t)(256+c)*NPB + blockIdx.x] = bs;
        }
    }
}

// K8b: reduce partials -> core sums. 8 blocks x 256 thr = 32 waves; 512 (cls,c) pairs.
__global__ void k_cored(void* ws){
    const float* part = (const float*)((char*)ws+OFF_PART);
    float* csum = (float*)((char*)ws+OFF_CORESUMG);   // [512] contiguous (G then B)
    int gw = (blockIdx.x*256 + threadIdx.x) >> 6;
    int lane = threadIdx.x & 63;
    for(int pair = gw; pair < 512; pair += 32){
        float s = 0.f;
        for(int i=lane; i<NPB; i+=64) s += part[(size_t)pair*NPB + i];
        s = waveReduceSum(s);
        if(lane==0) csum[pair] = s;
    }
}

// K9: core means + their norms
__global__ void k_coremean(void* ws){
    int cls = blockIdx.x, c = threadIdx.x;
    int* cnts = (int*)((char*)ws+OFF_CNTS);
    float* sum  = (float*)((char*)ws + (cls? OFF_CORESUMB : OFF_CORESUMG));
    float* mean = (float*)((char*)ws + (cls? OFF_COREMEANB: OFF_COREMEANG));
    int n = cnts[2+cls];
    float m = sum[c]/(float)n;
    mean[c] = m;
    float ss = waveReduceSum(m*m);
    __shared__ float wsum[4];
    int lane = c & 63, wid = c >> 6;
    if(lane==0) wsum[wid]=ss;
    __syncthreads();
    if(c==0) ((float*)((char*)ws+OFF_NPOS))[cls] = sqrtf(wsum[0]+wsum[1]+wsum[2]+wsum[3]);
}

// K10: fused anchor norm + pos logit from fp16 feats. One wave per anchor.
__global__ void k_anchor(void* ws){
    int* pi = (int*)((char*)ws+OFF_PLANI);
    int ntot = pi[10], ng = pi[8];
    int tid = threadIdx.x;
    int lane = tid & 63, wid = tid >> 6;
    int a = blockIdx.x*4 + wid;
    if(a >= ntot) return;
    int cls = (a < ng) ? 0 : 1;
    const float* mean = (const float*)((char*)ws + (cls? OFF_COREMEANB : OFF_COREMEANG));
    const half_t* feat = (const half_t*)((char*)ws+OFF_FEATSH) + (size_t)a*C_;
    half4 f4 = *(const half4*)&feat[lane*4];
    float fx = (float)f4[0], fy = (float)f4[1], fz = (float)f4[2], fw = (float)f4[3];
    float4 m = *(const float4*)&mean[lane*4];
    float ss = fx*fx + fy*fy + fz*fz + fw*fw;
    float dd = fx*m.x + fy*m.y + fz*m.z + fw*m.w;
    ss = waveReduceSum(ss); dd = waveReduceSum(dd);
    if(lane==0){
        float na = sqrtf(ss);
        float npos = ((float*)((char*)ws+OFF_NPOS))[cls];
        float den = fmaxf(na*npos, 1e-8f);
        ((float*)((char*)ws+OFF_NA))[a]   = na;
        ((float*)((char*)ws+OFF_RNA))[a]  = 1.0f/na;
        ((float*)((char*)ws+OFF_PLOG))[a] = (dd/den)*RTAU_;
    }
}

// ---------------------------------------------------------------------------
// K11 v6: LDS-staged double-buffered MFMA sim-GEMM + chunk LSE.
// Block = 128 anchors x 112 negs (one chunk), K=256 in 4 steps of 64.
// A/B tiles staged to LDS via global_load_lds (16B DMA, no dest VGPRs),
// double-buffered (m97 2-barrier schedule). XOR-swizzle byte^=(row&7)<<4
// applied on the *global source* side (gload_lds writes linearly) and on
// the ds_read side -> conflict-free b128 fragment reads.
// Wave tile: 32 anchors (2 MFMA rows) x 112 negs (7 cols), same MFMA
// sequence/order as v5 -> bit-identical numerics.
// ---------------------------------------------------------------------------
#define KSTEP 64
#define NKS 4           // 256 / 64
#define NCH_A 16        // 128 rows * 128B / 1KB-per-wave-DMA-chunk
#define NCH_B 14        // 112 rows * 128B / 1KB

__device__ __forceinline__ void k_loss_stage(const half_t* __restrict__ fh,
    half_t* Ab, half_t* Bb, int wv, int lane, int ks,
    int abase, int a0b, int n_a, int negbase, int f, int cs, int nb, int ng){
    #pragma unroll 1
    for(int ch = wv; ch < NCH_A + NCH_B; ch += 4){
        if(ch < NCH_A){
            int s = (ch<<6) | lane;
            int r = s >> 3, cg = s & 7;
            int ar = a0b + r; if(ar >= n_a) ar = a0b;     // safe duplicate row
            size_t off = (size_t)(abase + ar)*512 + (size_t)(ks*128)
                       + (size_t)((cg*16) ^ ((r&7)<<4));  // pre-swizzled source
            gl_lds16((const char*)fh + off, (char*)Ab + (ch<<10));
        } else {
            int cb = ch - NCH_A;
            int s = (cb<<6) | lane;
            int r = s >> 3, cg = s & 7;
            int kk = (r < cs) ? r : 0;                     // masked cols -> safe row
            int i = negbase + f*100 + kk;
            int fi = (i < nb) ? (ng + i) : (i - nb);
            size_t off = (size_t)fi*512 + (size_t)(ks*128)
                       + (size_t)((cg*16) ^ ((r&7)<<4));
            gl_lds16((const char*)fh + off, (char*)Bb + (cb<<10));
        }
    }
}

__global__ __launch_bounds__(256, 2) void k_loss(void* ws){
    __shared__ __attribute__((aligned(16))) half_t As[2][128*KSTEP]; // 2x16KB
    __shared__ __attribute__((aligned(16))) half_t Bs[2][112*KSTEP]; // 2x14KB
    __shared__ float redsum[4];

    int at = blockIdx.x, f = blockIdx.y, l = blockIdx.z;
    int* pi = (int*)((char*)ws+OFF_PLANI);
    int ng = pi[8], nb = pi[9], ntot = pi[10], nbg = pi[11];
    int n_a = l ? (ntot-nbg) : nbg;
    int nfull = n_a/100, rem = n_a%100;
    int nch = nfull + (rem?1:0);
    if(f >= nch) return;
    int cs = (f < nfull) ? 100 : rem;
    int a0b = at*128;
    if(a0b >= n_a) return;
    int abase   = l ? nbg : 0;
    int negbase = l ? nbg : 0;
    const half_t* fh     = (const half_t*)((char*)ws+OFF_FEATSH);
    const float* rnaArr  = (const float*)((char*)ws+OFF_RNA);
    const float* plogArr = (const float*)((char*)ws+OFF_PLOG);

    int tid = threadIdx.x;
    int wv = tid >> 6, lane = tid & 63;
    int qd = lane >> 4, ln = lane & 15;
    int qd16 = qd*16;
    int a0 = a0b + wv*32;

    // per-lane rnn for the 7 neg col-tiles (epilogue only)
    float rnn[7];
    #pragma unroll
    for(int t=0;t<7;t++){
        int k = 16*t + ln;
        float rn = 1.0f;
        if(k < cs){
            int i = negbase + f*100 + k;
            int fi = (i < nb) ? (ng + i) : (i - nb);
            rn = rnaArr[fi];
        }
        rnn[t] = rn;
    }

    f32x4 acc[2][7];
    #pragma unroll
    for(int i=0;i<2;i++)
        #pragma unroll
        for(int t=0;t<7;t++) acc[i][t] = (f32x4){0.f,0.f,0.f,0.f};

    // fragment row indices (in-tile) and their swizzle keys
    int ra0 = wv*32 + ln;         // & 15 rows of first MFMA row-tile
    int ra1 = ra0 + 16;
    int swa = (ra0 & 7) << 4;     // (ra1&7) == (ra0&7)
    int swb = (ln  & 7) << 4;     // (rb&7) == (ln&7) for all t

    // prologue: stage K-step 0 into buffer 0
    k_loss_stage(fh, As[0], Bs[0], wv, lane, 0, abase, a0b, n_a, negbase, f, cs, nb, ng);
    __syncthreads();

    int buf = 0;
    #pragma unroll 1
    for(int ks=0; ks<NKS; ks++){
        if(ks < NKS-1)
            k_loss_stage(fh, As[buf^1], Bs[buf^1], wv, lane, ks+1,
                         abase, a0b, n_a, negbase, f, cs, nb, ng);
        const char* Ab = (const char*)As[buf];
        const char* Bb = (const char*)Bs[buf];
        #pragma unroll
        for(int sub=0; sub<2; sub++){
            int cbb = sub*64 + qd16;
            half8 af0 = *(const half8*)(Ab + ra0*128 + (cbb ^ swa));
            half8 af1 = *(const half8*)(Ab + ra1*128 + (cbb ^ swa));
            #pragma unroll
            for(int t=0;t<7;t++){
                int rb = 16*t + ln;
                half8 bf = *(const half8*)(Bb + rb*128 + (cbb ^ swb));
                acc[0][t] = __builtin_amdgcn_mfma_f32_16x16x32_f16(af0, bf, acc[0][t], 0,0,0);
                acc[1][t] = __builtin_amdgcn_mfma_f32_16x16x32_f16(af1, bf, acc[1][t], 0,0,0);
            }
        }
        __syncthreads();
        buf ^= 1;
    }

    // epilogue: per-lane exp-sums over its 7 n-cols, 16-lane quad reduce
    float myval = 0.f;
    #pragma unroll
    for(int ta=0; ta<2; ta++){
        #pragma unroll
        for(int r=0;r<4;r++){
            int a = a0 + 16*ta + 4*qd + r;
            float ra = (a < n_a) ? rnaArr[abase+a]*RTAU_ : 0.f;
            float s = 0.f;
            #pragma unroll
            for(int tn=0;tn<7;tn++){
                if(16*tn + ln < cs)
                    s += __expf(acc[ta][tn][r] * ra * rnn[tn]);
            }
            if(a >= n_a) s = 0.f;
            #pragma unroll
            for(int off=8; off; off>>=1) s += __shfl_down(s, off, 64);
            if(ln == 0 && a < n_a){
                float plog = plogArr[abase+a];
                myval += __logf(s + __expf(plog)) - plog;
            }
        }
    }
    myval = waveReduceSum(myval);
    if(lane==0) redsum[wv] = myval;
    __syncthreads();
    if(tid==0)
        atomicAdd((float*)((char*)ws+OFF_CHUNKSUM) + l*NCHUNK_MAX + f,
                  redsum[0]+redsum[1]+redsum[2]+redsum[3]);
}

// K12: final scalar
__global__ void k_final(void* ws, float* out){
    int* pi = (int*)((char*)ws+OFF_PLANI);
    int ntot = pi[10], nbg = pi[11];
    float* csum = (float*)((char*)ws+OFF_CHUNKSUM);
    float total = 0.f;
    for(int l=0;l<2;l++){
        int n_a = l ? (ntot-nbg) : nbg;
        int nfull = n_a/100, rem = n_a%100;
        int nch = nfull + (rem?1:0);
        float s = 0.f;
        for(int f=0; f<nch; f++) s += csum[l*NCHUNK_MAX+f]/(float)n_a;
        total += s/(float)nch;
    }
    *out = total;
}

extern "C" void kernel_launch(void* const* d_in, const int* in_sizes, int n_in,
                              void* d_out, int out_size, void* d_ws, size_t ws_size,
                              hipStream_t stream){
    const float* x      = (const float*)d_in[0];   // (1,256,512,512)
    const float* logits = (const float*)d_in[1];   // (1,2,512,512)
    const int*   seg    = (const int*)d_in[2];     // (1,512,512)
    float* out = (float*)d_out;

    hipMemsetAsync(d_ws, 0, ZERO_BYTES, stream);
    k_conf<<<256,256,0,stream>>>(logits, seg, d_ws);
    k_plan1<<<1,1,0,stream>>>(d_ws);
    k_norm<<<1024,256,0,stream>>>(x, d_ws);
    k_poolcount<<<16,256,0,stream>>>(logits, seg, d_ws);
    k_scan<<<4,256,0,stream>>>(d_ws);
    k_plan2<<<1,1,0,stream>>>(d_ws);
    k_fill<<<16,256,0,stream>>>(logits, seg, d_ws);
    dim3 gg(128, 16);
    k_gather<<<gg,256,0,stream>>>(x, d_ws);
    k_core<<<NPB,256,0,stream>>>(x, logits, seg, d_ws);
    k_cored<<<8,256,0,stream>>>(d_ws);
    k_coremean<<<2,256,0,stream>>>(d_ws);
    k_anchor<<<2048,256,0,stream>>>(d_ws);
    dim3 g(32, NCHUNK_MAX, 2);
    k_loss<<<g,256,0,stream>>>(d_ws);
    k_final<<<1,1,0,stream>>>(d_ws, out);
}

// Round 2
// 551.221 us; speedup vs baseline: 1.3285x; 1.1872x over previous
//
#include <hip/hip_runtime.h>
#include <math.h>

#define HW 262144
#define C_ 256
#define SAMPLE_NUM_ 4096
#define TAU_ 0.07f
#define RTAU_ (1.0f/0.07f)
#define THRESH_ 0.8f
#define NCHUNK_MAX 41
#define NPB 512              // k_core partial blocks

typedef _Float16 half_t;
typedef __attribute__((ext_vector_type(4))) _Float16 half4;
typedef __attribute__((ext_vector_type(8))) _Float16 half8;
typedef __attribute__((ext_vector_type(4))) float f32x4;

// ---- ws byte offsets ----
#define OFF_GSUM   0          // double
#define OFF_BSUM   8          // double
#define OFF_CNTS   16         // int[4]: gcnt,bcnt,gcoreCnt,bcoreCnt
#define OFF_MGC    64         // double[2]: mgc, mbc
#define OFF_PLANI  96         // int[16]
#define OFF_CORESUMG 256      // float[256]
#define OFF_CORESUMB 1280     // float[256] (contiguous after CORESUMG)
#define OFF_CHUNKSUM 2304     // float[82]
#define OFF_COREMEANG 2688    // float[256]
#define OFF_COREMEANB 3712    // float[256]
#define OFF_NPOS   4736       // float[2]
#define ZERO_BYTES 16384
#define OFF_RNORM  16384                        // float[262144]
#define OFF_CNTPOOL (OFF_RNORM + 262144*4)      // int[4][4096]
#define OFF_OFFPOOL (OFF_CNTPOOL + 4*4096*4)    // int[4][4096]
#define OFF_TOTALS  (OFF_OFFPOOL + 4*4096*4)    // int[4] (+pad)
#define OFF_APIX    (OFF_TOTALS + 64)           // int[8192]
#define OFF_NA      (OFF_APIX + 8192*4)         // float[8192]
#define OFF_PLOG    (OFF_NA + 8192*4)           // float[8192]
#define OFF_RNA     (OFF_PLOG + 8192*4)         // float[8192]
#define OFF_FEATSH  (OFF_RNA + 8192*4)          // half[8192*256]  (4 MB, 16B-aligned)
#define OFF_PART    (OFF_FEATSH + 8192*256*2)   // float[512][NPB] (1 MB)

__device__ __forceinline__ float waveReduceSum(float v){
    for(int off=32; off; off>>=1) v += __shfl_down(v, off, 64);
    return v;
}
__device__ __forceinline__ int waveReduceSumI(int v){
    for(int off=32; off; off>>=1) v += __shfl_down(v, off, 64);
    return v;
}

// async global->LDS DMA, 16B per lane; LDS dest = wave-uniform base + lane*16
typedef __attribute__((address_space(1))) void as1_void;
typedef __attribute__((address_space(3))) void as3_void;
__device__ __forceinline__ void gl_lds16(const void* g, void* l){
    __builtin_amdgcn_global_load_lds((as1_void*)g, (as3_void*)l, 16, 0, 0);
}

// K1: confidence sums/counts + core counts (block-reduced, 1 atomic set per block)
__global__ void k_conf(const float* __restrict__ logits, const int* __restrict__ seg, void* ws){
    int tid = blockIdx.x*blockDim.x + threadIdx.x;
    int stride = gridDim.x*blockDim.x;
    float gs=0.f, bs=0.f; int gc=0, bc=0, gcc=0, bcc=0;
    for(int p=tid; p<HW; p+=stride){
        int s = seg[p];
        float l0 = logits[p], l1 = logits[HW+p];
        if(s==1){ gs += l1; gc++; if(l1 >= THRESH_) gcc++; }
        else    { bs += l0; bc++; if(l0 >= THRESH_) bcc++; }
    }
    gs = waveReduceSum(gs); bs = waveReduceSum(bs);
    gc = waveReduceSumI(gc); bc = waveReduceSumI(bc);
    gcc = waveReduceSumI(gcc); bcc = waveReduceSumI(bcc);
    __shared__ float rf[8];
    __shared__ int   ri[16];
    int lane = threadIdx.x & 63, wid = threadIdx.x >> 6;
    if(lane==0){
        rf[wid]=gs; rf[4+wid]=bs;
        ri[wid]=gc; ri[4+wid]=bc; ri[8+wid]=gcc; ri[12+wid]=bcc;
    }
    __syncthreads();
    if(threadIdx.x==0){
        float G=rf[0]+rf[1]+rf[2]+rf[3], B=rf[4]+rf[5]+rf[6]+rf[7];
        int GC=ri[0]+ri[1]+ri[2]+ri[3], BC=ri[4]+ri[5]+ri[6]+ri[7];
        int GCC=ri[8]+ri[9]+ri[10]+ri[11], BCC=ri[12]+ri[13]+ri[14]+ri[15];
        atomicAdd((double*)((char*)ws+OFF_GSUM), (double)G);
        atomicAdd((double*)((char*)ws+OFF_BSUM), (double)B);
        int* c = (int*)((char*)ws+OFF_CNTS);
        atomicAdd(c+0, GC); atomicAdd(c+1, BC);
        atomicAdd(c+2, GCC); atomicAdd(c+3, BCC);
    }
}

// K2: plan part 1
__global__ void k_plan1(void* ws){
    double gs = *(double*)((char*)ws+OFF_GSUM);
    double bs = *(double*)((char*)ws+OFF_BSUM);
    int* cnts = (int*)((char*)ws+OFF_CNTS);
    double mgc = gs / ((double)cnts[0] + 1e-8);
    double mbc = bs / ((double)cnts[1] + 1e-8);
    double* md = (double*)((char*)ws+OFF_MGC);
    md[0]=mgc; md[1]=mbc;
    int* pi = (int*)((char*)ws+OFF_PLANI);
    int eg = (int)(SAMPLE_NUM_*(1.0-mgc)); if(eg<1) eg=1;
    int eb = (int)(SAMPLE_NUM_*(1.0-mbc)); if(eb<1) eb=1;
    pi[0]=eg; pi[1]=SAMPLE_NUM_-eg; pi[2]=eb; pi[3]=SAMPLE_NUM_-eb;
}

// K3: per-pixel reciprocal channel norms; fully coalesced
__global__ void k_norm(const float* __restrict__ x, void* ws){
    int p = blockIdx.x*blockDim.x + threadIdx.x;
    float ss = 0.f;
    #pragma unroll 8
    for(int c=0;c<C_;c++){ float v = x[(size_t)c*HW + p]; ss += v*v; }
    ((float*)((char*)ws+OFF_RNORM))[p] = 1.0f / fmaxf(sqrtf(ss), 1e-12f);
}

// K4 v2: wave-parallel pool counts. One wave per 64-pixel chunk; coalesced
// loads; counts via ballot+popcount. Identical classification -> identical cnt.
__global__ void k_poolcount(const float* __restrict__ logits, const int* __restrict__ seg, void* ws){
    int gtid = blockIdx.x*blockDim.x + threadIdx.x;   // 262144 threads
    int t = gtid >> 6;                                // chunk = wave id, [0,4096)
    int lane = gtid & 63;
    const double* md = (const double*)((char*)ws+OFF_MGC);
    double mgc = md[0], mbc = md[1];
    int p = t*64 + lane;
    int s = seg[p]; int q;
    if(s==1) q = ((double)logits[HW+p] >= mgc) ? 0 : 1;
    else     q = ((double)logits[p]    >= mbc) ? 2 : 3;
    unsigned long long m0 = __ballot(q==0);
    unsigned long long m1 = __ballot(q==1);
    unsigned long long m2 = __ballot(q==2);
    unsigned long long m3 = __ballot(q==3);
    if(lane < 4){
        unsigned long long m = (lane==0)?m0:(lane==1)?m1:(lane==2)?m2:m3;
        ((int*)((char*)ws+OFF_CNTPOOL))[lane*4096 + t] = __popcll(m);
    }
}

// K5: exclusive scan over 4096 thread-chunk counts, one block per pool
__global__ void k_scan(void* ws){
    int q = blockIdx.x, j = threadIdx.x;
    int* cp = (int*)((char*)ws+OFF_CNTPOOL) + q*4096;
    int* op = (int*)((char*)ws+OFF_OFFPOOL) + q*4096;
    __shared__ int s[256];
    int base = j*16, sj=0, loc[16];
    for(int i=0;i<16;i++){ loc[i]=cp[base+i]; sj+=loc[i]; }
    s[j]=sj; __syncthreads();
    for(int off=1; off<256; off<<=1){
        int v = (j>=off)? s[j-off] : 0;
        __syncthreads();
        s[j] += v;
        __syncthreads();
    }
    int ex = s[j]-sj;
    for(int i=0;i<16;i++){ op[base+i]=ex; ex+=loc[i]; }
    if(j==255) ((int*)((char*)ws+OFF_TOTALS))[q] = s[255];
}

// K5b: plan part 2
__global__ void k_plan2(void* ws){
    int* pi = (int*)((char*)ws+OFF_PLANI);
    int* tot = (int*)((char*)ws+OFF_TOTALS);
    int sge = min(tot[0], pi[0]);
    int sgh = min(tot[1], pi[1]);
    int sbe = min(tot[2], pi[2]);
    int sbh = min(tot[3], pi[3]);
    int ng = sge+sgh, nb = sbe+sbh;
    pi[4]=sge; pi[5]=sgh; pi[6]=sbe; pi[7]=sbh;
    pi[8]=ng; pi[9]=nb; pi[10]=ng+nb; pi[11]=nb;
    pi[12]=0; pi[13]=sge; pi[14]=ng; pi[15]=ng+sbe;
}

// K6 v2: wave-parallel deterministic compaction. Rank within chunk =
// ballot-prefix (preserves pixel order exactly like the serial loop).
__global__ void k_fill(const float* __restrict__ logits, const int* __restrict__ seg, void* ws){
    int gtid = blockIdx.x*blockDim.x + threadIdx.x;   // 262144 threads
    int t = gtid >> 6;
    int lane = gtid & 63;
    const double* md = (const double*)((char*)ws+OFF_MGC);
    double mgc = md[0], mbc = md[1];
    int* op = (int*)((char*)ws+OFF_OFFPOOL);
    int* pi = (int*)((char*)ws+OFF_PLANI);
    int* apix = (int*)((char*)ws+OFF_APIX);
    int p = t*64 + lane;
    int s = seg[p]; int q;
    if(s==1) q = ((double)logits[HW+p] >= mgc) ? 0 : 1;
    else     q = ((double)logits[p]    >= mbc) ? 2 : 3;
    unsigned long long m0 = __ballot(q==0);
    unsigned long long m1 = __ballot(q==1);
    unsigned long long m2 = __ballot(q==2);
    unsigned long long m3 = __ballot(q==3);
    unsigned long long mq = (q==0)?m0:(q==1)?m1:(q==2)?m2:m3;
    unsigned long long below = (1ULL << lane) - 1ULL;
    int prefix = __popcll(mq & below);
    int r = op[q*4096 + t] + prefix;
    if(r < pi[4+q]) apix[pi[12+q] + r] = p;
}

// K7: gather + normalize anchor features -> fp16 table. grid (128 a-tiles, 16 ch-groups).
__global__ void k_gather(const float* __restrict__ x, void* ws){
    int* pi = (int*)((char*)ws+OFF_PLANI);
    int ntot = pi[10];
    int a0 = blockIdx.x*64;
    int c0 = blockIdx.y*16;
    int tid = threadIdx.x;
    int lane = tid & 63, wid = tid >> 6;
    __shared__ float T[16][65];
    int a = a0 + lane;
    int p = -1; float rn = 0.f;
    if(a < ntot){
        p = ((int*)((char*)ws+OFF_APIX))[a];
        rn = ((float*)((char*)ws+OFF_RNORM))[p];
    }
    #pragma unroll
    for(int i=0;i<4;i++){
        int c = c0 + wid*4 + i;
        float v = (p>=0) ? x[(size_t)c*HW + p]*rn : 0.0f;
        T[wid*4+i][lane] = v;
    }
    __syncthreads();
    int aL = tid & 63, cq = tid >> 6;
    half4 h;
    h[0] = (half_t)T[cq*4+0][aL]; h[1] = (half_t)T[cq*4+1][aL];
    h[2] = (half_t)T[cq*4+2][aL]; h[3] = (half_t)T[cq*4+3][aL];
    *(half4*)&((half_t*)((char*)ws+OFF_FEATSH))[(size_t)(a0+aL)*C_ + c0 + cq*4] = h;
}

// K8a: per-channel core sums -> per-block partials (no contended atomics)
__global__ void k_core(const float* __restrict__ x, const float* __restrict__ logits,
                       const int* __restrict__ seg, void* ws){
    __shared__ float wg[512], wb[512];
    int p0 = blockIdx.x*512;
    int tid = threadIdx.x;
    const float* rnorm = (const float*)((char*)ws+OFF_RNORM);
    for(int i=tid; i<512; i+=256){
        int p = p0+i; int s = seg[p];
        float rn = rnorm[p];
        wg[i] = (s==1 && logits[HW+p] >= THRESH_) ? rn : 0.0f;
        wb[i] = (s==0 && logits[p]    >= THRESH_) ? rn : 0.0f;
    }
    __syncthreads();
    float* part = (float*)((char*)ws+OFF_PART);
    int lane = tid & 63, wid = tid >> 6;
    for(int c=wid; c<C_; c+=4){
        float gs=0.f, bs=0.f;
        #pragma unroll
        for(int i=0;i<8;i++){
            int idx = i*64 + lane;
            float xv = x[(size_t)c*HW + p0 + idx];
            gs += xv*wg[idx]; bs += xv*wb[idx];
        }
        gs = waveReduceSum(gs); bs = waveReduceSum(bs);
        if(lane==0){
            part[(size_t)c*NPB + blockIdx.x]       = gs;
            part[(size_t)(256+c)*NPB + blockIdx.x] = bs;
        }
    }
}

// K8b: reduce partials -> core sums. 8 blocks x 256 thr = 32 waves; 512 (cls,c) pairs.
__global__ void k_cored(void* ws){
    const float* part = (const float*)((char*)ws+OFF_PART);
    float* csum = (float*)((char*)ws+OFF_CORESUMG);   // [512] contiguous (G then B)
    int gw = (blockIdx.x*256 + threadIdx.x) >> 6;
    int lane = threadIdx.x & 63;
    for(int pair = gw; pair < 512; pair += 32){
        float s = 0.f;
        for(int i=lane; i<NPB; i+=64) s += part[(size_t)pair*NPB + i];
        s = waveReduceSum(s);
        if(lane==0) csum[pair] = s;
    }
}

// K9: core means + their norms
__global__ void k_coremean(void* ws){
    int cls = blockIdx.x, c = threadIdx.x;
    int* cnts = (int*)((char*)ws+OFF_CNTS);
    float* sum  = (float*)((char*)ws + (cls? OFF_CORESUMB : OFF_CORESUMG));
    float* mean = (float*)((char*)ws + (cls? OFF_COREMEANB: OFF_COREMEANG));
    int n = cnts[2+cls];
    float m = sum[c]/(float)n;
    mean[c] = m;
    float ss = waveReduceSum(m*m);
    __shared__ float wsum[4];
    int lane = c & 63, wid = c >> 6;
    if(lane==0) wsum[wid]=ss;
    __syncthreads();
    if(c==0) ((float*)((char*)ws+OFF_NPOS))[cls] = sqrtf(wsum[0]+wsum[1]+wsum[2]+wsum[3]);
}

// K10: fused anchor norm + pos logit from fp16 feats. One wave per anchor.
__global__ void k_anchor(void* ws){
    int* pi = (int*)((char*)ws+OFF_PLANI);
    int ntot = pi[10], ng = pi[8];
    int tid = threadIdx.x;
    int lane = tid & 63, wid = tid >> 6;
    int a = blockIdx.x*4 + wid;
    if(a >= ntot) return;
    int cls = (a < ng) ? 0 : 1;
    const float* mean = (const float*)((char*)ws + (cls? OFF_COREMEANB : OFF_COREMEANG));
    const half_t* feat = (const half_t*)((char*)ws+OFF_FEATSH) + (size_t)a*C_;
    half4 f4 = *(const half4*)&feat[lane*4];
    float fx = (float)f4[0], fy = (float)f4[1], fz = (float)f4[2], fw = (float)f4[3];
    float4 m = *(const float4*)&mean[lane*4];
    float ss = fx*fx + fy*fy + fz*fz + fw*fw;
    float dd = fx*m.x + fy*m.y + fz*m.z + fw*m.w;
    ss = waveReduceSum(ss); dd = waveReduceSum(dd);
    if(lane==0){
        float na = sqrtf(ss);
        float npos = ((float*)((char*)ws+OFF_NPOS))[cls];
        float den = fmaxf(na*npos, 1e-8f);
        ((float*)((char*)ws+OFF_NA))[a]   = na;
        ((float*)((char*)ws+OFF_RNA))[a]  = 1.0f/na;
        ((float*)((char*)ws+OFF_PLOG))[a] = (dd/den)*RTAU_;
    }
}

// ---------------------------------------------------------------------------
// K11 v7: LDS-staged double-buffered MFMA sim-GEMM, KSTEP=32.
// LDS per buffer = A[128][32] (8KB) + B[112][32] (7KB) = 15KB; 2 buffers =
// 30KB -> 4+ blocks/CU (was 2 at KSTEP=64). Fragment reads are contiguous
// 1KB per wave (row stride 64B, lanes cover distinct 16B slots) -> bank-
// conflict-free WITHOUT any swizzle; staging is linear gl_lds16 with
// per-wave precomputed chunk pointers (+64B per K-step).
// K accumulation order identical to v5/v6 -> bit-identical numerics.
// ---------------------------------------------------------------------------
#define KSTEP 32
#define NKS 8            // 256 / 32
#define NCHUNKS 15       // 8 A-chunks (1KB each) + 7 B-chunks
#define TILEB 15360      // bytes per buffer

__global__ __launch_bounds__(256, 4) void k_loss(void* ws){
    __shared__ __attribute__((aligned(16))) char S[2][TILEB];
    __shared__ float redsum[4];

    int at = blockIdx.x, f = blockIdx.y, l = blockIdx.z;
    int* pi = (int*)((char*)ws+OFF_PLANI);
    int ng = pi[8], nb = pi[9], ntot = pi[10], nbg = pi[11];
    int n_a = l ? (ntot-nbg) : nbg;
    int nfull = n_a/100, rem = n_a%100;
    int nch = nfull + (rem?1:0);
    if(f >= nch) return;
    int cs = (f < nfull) ? 100 : rem;
    int a0b = at*128;
    if(a0b >= n_a) return;
    int abase   = l ? nbg : 0;
    int negbase = l ? nbg : 0;
    const char* fhB      = (const char*)((char*)ws+OFF_FEATSH);
    const float* rnaArr  = (const float*)((char*)ws+OFF_RNA);
    const float* plogArr = (const float*)((char*)ws+OFF_PLOG);

    int tid = threadIdx.x;
    int wv = tid >> 6, lane = tid & 63;
    int qd = lane >> 4, ln = lane & 15;
    int a0 = a0b + wv*32;

    // per-lane rnn for the 7 neg col-tiles (epilogue only)
    float rnn[7];
    #pragma unroll
    for(int t=0;t<7;t++){
        int k = 16*t + ln;
        float rn = 1.0f;
        if(k < cs){
            int i = negbase + f*100 + k;
            int fi = (i < nb) ? (ng + i) : (i - nb);
            rn = rnaArr[fi];
        }
        rnn[t] = rn;
    }

    // precompute this wave's staging chunk sources (static-indexed, stays in regs)
    // chunk ch<8: A rows [ch*16, ch*16+16); ch>=8: B rows [(ch-8)*16, ...)
    const char* gsrc[4];
    int subrow = lane >> 2;          // row within chunk [0,16)
    int colb   = (lane & 3) * 16;    // byte column within 64B row
    #pragma unroll
    for(int j=0;j<4;j++){
        int ch = wv + 4*j;
        gsrc[j] = fhB;
        if(ch < NCHUNKS){
            if(ch < 8){
                int r = ch*16 + subrow;
                int ar = a0b + r; if(ar >= n_a) ar = a0b;
                gsrc[j] = fhB + (size_t)(abase + ar)*512 + colb;
            } else {
                int rb = (ch-8)*16 + subrow;
                int kk = (rb < cs) ? rb : 0;
                int i = negbase + f*100 + kk;
                int fi = (i < nb) ? (ng + i) : (i - nb);
                gsrc[j] = fhB + (size_t)fi*512 + colb;
            }
        }
    }

    f32x4 acc[2][7];
    #pragma unroll
    for(int i=0;i<2;i++)
        #pragma unroll
        for(int t=0;t<7;t++) acc[i][t] = (f32x4){0.f,0.f,0.f,0.f};

    // prologue: stage K-step 0 into buffer 0
    #pragma unroll
    for(int j=0;j<4;j++){
        int ch = wv + 4*j;
        if(ch < NCHUNKS) gl_lds16(gsrc[j], (char*)S[0] + (ch<<10));
    }
    __syncthreads();

    int buf = 0;
    #pragma unroll 1
    for(int ks=0; ks<NKS; ks++){
        if(ks < NKS-1){
            #pragma unroll
            for(int j=0;j<4;j++){
                int ch = wv + 4*j;
                if(ch < NCHUNKS)
                    gl_lds16(gsrc[j] + (ks+1)*64, (char*)S[buf^1] + (ch<<10));
            }
        }
        const char* Ab = (const char*)S[buf];
        const char* Bb = (const char*)S[buf] + 8192;
        half8 af0 = *(const half8*)(Ab + (wv*32 + ln)*64 + qd*16);
        half8 af1 = *(const half8*)(Ab + (wv*32 + 16 + ln)*64 + qd*16);
        #pragma unroll
        for(int t=0;t<7;t++){
            half8 bf = *(const half8*)(Bb + (16*t + ln)*64 + qd*16);
            acc[0][t] = __builtin_amdgcn_mfma_f32_16x16x32_f16(af0, bf, acc[0][t], 0,0,0);
            acc[1][t] = __builtin_amdgcn_mfma_f32_16x16x32_f16(af1, bf, acc[1][t], 0,0,0);
        }
        __syncthreads();
        buf ^= 1;
    }

    // epilogue: per-lane exp-sums over its 7 n-cols, 16-lane quad reduce
    float myval = 0.f;
    #pragma unroll
    for(int ta=0; ta<2; ta++){
        #pragma unroll
        for(int r=0;r<4;r++){
            int a = a0 + 16*ta + 4*qd + r;
            float ra = (a < n_a) ? rnaArr[abase+a]*RTAU_ : 0.f;
            float s = 0.f;
            #pragma unroll
            for(int tn=0;tn<7;tn++){
                if(16*tn + ln < cs)
                    s += __expf(acc[ta][tn][r] * ra * rnn[tn]);
            }
            if(a >= n_a) s = 0.f;
            #pragma unroll
            for(int off=8; off; off>>=1) s += __shfl_down(s, off, 64);
            if(ln == 0 && a < n_a){
                float plog = plogArr[abase+a];
                myval += __logf(s + __expf(plog)) - plog;
            }
        }
    }
    myval = waveReduceSum(myval);
    if(lane==0) redsum[wv] = myval;
    __syncthreads();
    if(tid==0)
        atomicAdd((float*)((char*)ws+OFF_CHUNKSUM) + l*NCHUNK_MAX + f,
                  redsum[0]+redsum[1]+redsum[2]+redsum[3]);
}

// K12: final scalar
__global__ void k_final(void* ws, float* out){
    int* pi = (int*)((char*)ws+OFF_PLANI);
    int ntot = pi[10], nbg = pi[11];
    float* csum = (float*)((char*)ws+OFF_CHUNKSUM);
    float total = 0.f;
    for(int l=0;l<2;l++){
        int n_a = l ? (ntot-nbg) : nbg;
        int nfull = n_a/100, rem = n_a%100;
        int nch = nfull + (rem?1:0);
        float s = 0.f;
        for(int f=0; f<nch; f++) s += csum[l*NCHUNK_MAX+f]/(float)n_a;
        total += s/(float)nch;
    }
    *out = total;
}

extern "C" void kernel_launch(void* const* d_in, const int* in_sizes, int n_in,
                              void* d_out, int out_size, void* d_ws, size_t ws_size,
                              hipStream_t stream){
    const float* x      = (const float*)d_in[0];   // (1,256,512,512)
    const float* logits = (const float*)d_in[1];   // (1,2,512,512)
    const int*   seg    = (const int*)d_in[2];     // (1,512,512)
    float* out = (float*)d_out;

    hipMemsetAsync(d_ws, 0, ZERO_BYTES, stream);
    k_conf<<<256,256,0,stream>>>(logits, seg, d_ws);
    k_plan1<<<1,1,0,stream>>>(d_ws);
    k_norm<<<1024,256,0,stream>>>(x, d_ws);
    k_poolcount<<<1024,256,0,stream>>>(logits, seg, d_ws);
    k_scan<<<4,256,0,stream>>>(d_ws);
    k_plan2<<<1,1,0,stream>>>(d_ws);
    k_fill<<<1024,256,0,stream>>>(logits, seg, d_ws);
    dim3 gg(128, 16);
    k_gather<<<gg,256,0,stream>>>(x, d_ws);
    k_core<<<NPB,256,0,stream>>>(x, logits, seg, d_ws);
    k_cored<<<8,256,0,stream>>>(d_ws);
    k_coremean<<<2,256,0,stream>>>(d_ws);
    k_anchor<<<2048,256,0,stream>>>(d_ws);
    dim3 g(32, NCHUNK_MAX, 2);
    k_loss<<<g,256,0,stream>>>(d_ws);
    k_final<<<1,1,0,stream>>>(d_ws, out);
}

// Round 3
// 486.987 us; speedup vs baseline: 1.5038x; 1.1319x over previous
//
#include <hip/hip_runtime.h>
#include <math.h>

#define HW 262144
#define C_ 256
#define SAMPLE_NUM_ 4096
#define TAU_ 0.07f
#define RTAU_ (1.0f/0.07f)
#define THRESH_ 0.8f
#define NCHUNK_MAX 41
#define PREPB 4096           // k_prep blocks, 64 pixels each

typedef _Float16 half_t;
typedef __attribute__((ext_vector_type(4))) _Float16 half4;
typedef __attribute__((ext_vector_type(8))) _Float16 half8;
typedef __attribute__((ext_vector_type(4))) float f32x4;

// ---- ws byte offsets ----
#define OFF_GSUM   0          // double
#define OFF_BSUM   8          // double
#define OFF_CNTS   16         // int[4]: gcnt,bcnt,gcoreCnt,bcoreCnt
#define OFF_MGC    64         // double[2]: mgc, mbc
#define OFF_PLANI  96         // int[16]
#define OFF_CORESUMG 256      // float[256]
#define OFF_CORESUMB 1280     // float[256] (contiguous after CORESUMG)
#define OFF_CHUNKSUM 2304     // float[82]
#define OFF_COREMEANG 2688    // float[256]
#define OFF_COREMEANB 3712    // float[256]
#define OFF_NPOS   4736       // float[2]
#define ZERO_BYTES 16384
#define OFF_PIX2A  16384                        // int[262144] (reuses old RNORM slot)
#define OFF_CNTPOOL (OFF_PIX2A + 262144*4)      // int[4][4096]
#define OFF_OFFPOOL (OFF_CNTPOOL + 4*4096*4)    // int[4][4096]
#define OFF_TOTALS  (OFF_OFFPOOL + 4*4096*4)    // int[4] (+pad)
#define OFF_APIX    (OFF_TOTALS + 64)           // int[8192] (unused, kept for layout)
#define OFF_NA      (OFF_APIX + 8192*4)         // float[8192]
#define OFF_PLOG    (OFF_NA + 8192*4)           // float[8192]
#define OFF_RNA     (OFF_PLOG + 8192*4)         // float[8192]
#define OFF_FEATSH  (OFF_RNA + 8192*4)          // half[8192*256]  (4 MB, 16B-aligned)
#define OFF_PART    (OFF_FEATSH + 8192*256*2)   // float[PREPB][512] (8 MB)

__device__ __forceinline__ float waveReduceSum(float v){
    for(int off=32; off; off>>=1) v += __shfl_down(v, off, 64);
    return v;
}
__device__ __forceinline__ int waveReduceSumI(int v){
    for(int off=32; off; off>>=1) v += __shfl_down(v, off, 64);
    return v;
}

// async global->LDS DMA, 16B per lane; LDS dest = wave-uniform base + lane*16
typedef __attribute__((address_space(1))) void as1_void;
typedef __attribute__((address_space(3))) void as3_void;
__device__ __forceinline__ void gl_lds16(const void* g, void* l){
    __builtin_amdgcn_global_load_lds((as1_void*)g, (as3_void*)l, 16, 0, 0);
}

// K1: confidence sums/counts + core counts (block-reduced, 1 atomic set per block)
__global__ void k_conf(const float* __restrict__ logits, const int* __restrict__ seg, void* ws){
    int tid = blockIdx.x*blockDim.x + threadIdx.x;
    int stride = gridDim.x*blockDim.x;
    float gs=0.f, bs=0.f; int gc=0, bc=0, gcc=0, bcc=0;
    for(int p=tid; p<HW; p+=stride){
        int s = seg[p];
        float l0 = logits[p], l1 = logits[HW+p];
        if(s==1){ gs += l1; gc++; if(l1 >= THRESH_) gcc++; }
        else    { bs += l0; bc++; if(l0 >= THRESH_) bcc++; }
    }
    gs = waveReduceSum(gs); bs = waveReduceSum(bs);
    gc = waveReduceSumI(gc); bc = waveReduceSumI(bc);
    gcc = waveReduceSumI(gcc); bcc = waveReduceSumI(bcc);
    __shared__ float rf[8];
    __shared__ int   ri[16];
    int lane = threadIdx.x & 63, wid = threadIdx.x >> 6;
    if(lane==0){
        rf[wid]=gs; rf[4+wid]=bs;
        ri[wid]=gc; ri[4+wid]=bc; ri[8+wid]=gcc; ri[12+wid]=bcc;
    }
    __syncthreads();
    if(threadIdx.x==0){
        float G=rf[0]+rf[1]+rf[2]+rf[3], B=rf[4]+rf[5]+rf[6]+rf[7];
        int GC=ri[0]+ri[1]+ri[2]+ri[3], BC=ri[4]+ri[5]+ri[6]+ri[7];
        int GCC=ri[8]+ri[9]+ri[10]+ri[11], BCC=ri[12]+ri[13]+ri[14]+ri[15];
        atomicAdd((double*)((char*)ws+OFF_GSUM), (double)G);
        atomicAdd((double*)((char*)ws+OFF_BSUM), (double)B);
        int* c = (int*)((char*)ws+OFF_CNTS);
        atomicAdd(c+0, GC); atomicAdd(c+1, BC);
        atomicAdd(c+2, GCC); atomicAdd(c+3, BCC);
    }
}

// K2: plan part 1
__global__ void k_plan1(void* ws){
    double gs = *(double*)((char*)ws+OFF_GSUM);
    double bs = *(double*)((char*)ws+OFF_BSUM);
    int* cnts = (int*)((char*)ws+OFF_CNTS);
    double mgc = gs / ((double)cnts[0] + 1e-8);
    double mbc = bs / ((double)cnts[1] + 1e-8);
    double* md = (double*)((char*)ws+OFF_MGC);
    md[0]=mgc; md[1]=mbc;
    int* pi = (int*)((char*)ws+OFF_PLANI);
    int eg = (int)(SAMPLE_NUM_*(1.0-mgc)); if(eg<1) eg=1;
    int eb = (int)(SAMPLE_NUM_*(1.0-mbc)); if(eb<1) eb=1;
    pi[0]=eg; pi[1]=SAMPLE_NUM_-eg; pi[2]=eb; pi[3]=SAMPLE_NUM_-eb;
}

// K4 v3: wave-parallel pool counts + pix2a init (touches every pixel anyway)
__global__ void k_poolcount(const float* __restrict__ logits, const int* __restrict__ seg, void* ws){
    int gtid = blockIdx.x*blockDim.x + threadIdx.x;   // 262144 threads
    int t = gtid >> 6;                                // chunk = wave id, [0,4096)
    int lane = gtid & 63;
    const double* md = (const double*)((char*)ws+OFF_MGC);
    double mgc = md[0], mbc = md[1];
    int p = t*64 + lane;
    ((int*)((char*)ws+OFF_PIX2A))[p] = -1;
    int s = seg[p]; int q;
    if(s==1) q = ((double)logits[HW+p] >= mgc) ? 0 : 1;
    else     q = ((double)logits[p]    >= mbc) ? 2 : 3;
    unsigned long long m0 = __ballot(q==0);
    unsigned long long m1 = __ballot(q==1);
    unsigned long long m2 = __ballot(q==2);
    unsigned long long m3 = __ballot(q==3);
    if(lane < 4){
        unsigned long long m = (lane==0)?m0:(lane==1)?m1:(lane==2)?m2:m3;
        ((int*)((char*)ws+OFF_CNTPOOL))[lane*4096 + t] = __popcll(m);
    }
}

// K5: exclusive scan over 4096 thread-chunk counts, one block per pool
__global__ void k_scan(void* ws){
    int q = blockIdx.x, j = threadIdx.x;
    int* cp = (int*)((char*)ws+OFF_CNTPOOL) + q*4096;
    int* op = (int*)((char*)ws+OFF_OFFPOOL) + q*4096;
    __shared__ int s[256];
    int base = j*16, sj=0, loc[16];
    for(int i=0;i<16;i++){ loc[i]=cp[base+i]; sj+=loc[i]; }
    s[j]=sj; __syncthreads();
    for(int off=1; off<256; off<<=1){
        int v = (j>=off)? s[j-off] : 0;
        __syncthreads();
        s[j] += v;
        __syncthreads();
    }
    int ex = s[j]-sj;
    for(int i=0;i<16;i++){ op[base+i]=ex; ex+=loc[i]; }
    if(j==255) ((int*)((char*)ws+OFF_TOTALS))[q] = s[255];
}

// K5b: plan part 2
__global__ void k_plan2(void* ws){
    int* pi = (int*)((char*)ws+OFF_PLANI);
    int* tot = (int*)((char*)ws+OFF_TOTALS);
    int sge = min(tot[0], pi[0]);
    int sgh = min(tot[1], pi[1]);
    int sbe = min(tot[2], pi[2]);
    int sbh = min(tot[3], pi[3]);
    int ng = sge+sgh, nb = sbe+sbh;
    pi[4]=sge; pi[5]=sgh; pi[6]=sbe; pi[7]=sbh;
    pi[8]=ng; pi[9]=nb; pi[10]=ng+nb; pi[11]=nb;
    pi[12]=0; pi[13]=sge; pi[14]=ng; pi[15]=ng+sbe;
}

// K6 v3: wave-parallel deterministic compaction -> pix2a inverse map
__global__ void k_fill(const float* __restrict__ logits, const int* __restrict__ seg, void* ws){
    int gtid = blockIdx.x*blockDim.x + threadIdx.x;   // 262144 threads
    int t = gtid >> 6;
    int lane = gtid & 63;
    const double* md = (const double*)((char*)ws+OFF_MGC);
    double mgc = md[0], mbc = md[1];
    int* op = (int*)((char*)ws+OFF_OFFPOOL);
    int* pi = (int*)((char*)ws+OFF_PLANI);
    int p = t*64 + lane;
    int s = seg[p]; int q;
    if(s==1) q = ((double)logits[HW+p] >= mgc) ? 0 : 1;
    else     q = ((double)logits[p]    >= mbc) ? 2 : 3;
    unsigned long long m0 = __ballot(q==0);
    unsigned long long m1 = __ballot(q==1);
    unsigned long long m2 = __ballot(q==2);
    unsigned long long m3 = __ballot(q==3);
    unsigned long long mq = (q==0)?m0:(q==1)?m1:(q==2)?m2:m3;
    unsigned long long below = (1ULL << lane) - 1ULL;
    int prefix = __popcll(mq & below);
    int r = op[q*4096 + t] + prefix;
    if(r < pi[4+q]) ((int*)((char*)ws+OFF_PIX2A))[p] = pi[12+q] + r;
}

// ---------------------------------------------------------------------------
// K7 v2 (k_prep): single-pass x streamer. Per block: 64-pixel column tile in
// LDS (f32, XOR-swizzled [c][p^(c&31)] -> both access axes <=2-way conflicts).
// Computes: (a) per-pixel 1/||x|| (k_norm's job, kept in LDS only),
// (b) per-channel core partial sums (k_core's job, channel-per-thread),
// (c) fp16 anchor feature rows for anchors in this tile (k_gather's job,
// via pix2a inverse map). x is read from HBM exactly ONCE.
// 2 blocks/CU (70KB LDS) so pass-A streaming overlaps pass-B/C compute.
// ---------------------------------------------------------------------------
__global__ __launch_bounds__(256, 2) void k_prep(const float* __restrict__ x,
        const float* __restrict__ logits, const int* __restrict__ seg, void* ws){
    __shared__ float TS[256][64];     // 64 KB, [c][p ^ (c&31)]
    __shared__ float ssp[16][64];     // 4 KB
    __shared__ float rn[64], wgt[64], wbt[64];
    __shared__ int   hp[64], ha[64];
    __shared__ int   nhit_s;

    int p0 = blockIdx.x*64;
    int tid = threadIdx.x;
    int q = tid & 15, h = tid >> 4;   // pixel-quad, channel-slice (16ch each)

    // pass A: stream x -> LDS tile + per-pixel sumsq partials
    float ssx=0.f, ssy=0.f, ssz=0.f, ssw=0.f;
    #pragma unroll
    for(int i=0;i<16;i++){
        int c = h*16 + i;
        float4 v = *(const float4*)&x[(size_t)c*HW + p0 + q*4];
        ssx += v.x*v.x; ssy += v.y*v.y; ssz += v.z*v.z; ssw += v.w*v.w;
        int e3 = i & 3;                                  // compile-time per i
        int sbase = (q*4) ^ (((h&1)*16) + (i & ~3));
        float w0,w1,w2,w3;
        if(e3==0){ w0=v.x;w1=v.y;w2=v.z;w3=v.w; }
        else if(e3==1){ w0=v.y;w1=v.x;w2=v.w;w3=v.z; }
        else if(e3==2){ w0=v.z;w1=v.w;w2=v.x;w3=v.y; }
        else          { w0=v.w;w1=v.z;w2=v.y;w3=v.x; }
        float4 w; w.x=w0; w.y=w1; w.z=w2; w.w=w3;
        *(float4*)&TS[c][sbase] = w;
    }
    float4 sv; sv.x=ssx; sv.y=ssy; sv.z=ssz; sv.w=ssw;
    *(float4*)&ssp[h][q*4] = sv;
    __syncthreads();

    // rnorm + core weights + anchor hits (wave 0 only: threads 0..63)
    if(tid < 64){
        float ss = 0.f;
        #pragma unroll
        for(int hh=0; hh<16; hh++) ss += ssp[hh][tid];
        float r = 1.0f / fmaxf(sqrtf(ss), 1e-12f);
        rn[tid] = r;
        int p = p0 + tid;
        int s = seg[p];
        float l0 = logits[p], l1 = logits[HW+p];
        wgt[tid] = (s==1 && l1 >= THRESH_) ? r : 0.0f;
        wbt[tid] = (s==0 && l0 >= THRESH_) ? r : 0.0f;
        int a = ((const int*)((char*)ws+OFF_PIX2A))[p];
        unsigned long long m = __ballot(a >= 0);
        int pre = __popcll(m & ((1ULL<<tid)-1ULL));
        if(a >= 0){ hp[pre] = tid; ha[pre] = a; }
        if(tid==0) nhit_s = __popcll(m);
    }
    __syncthreads();

    // pass B: core sums, one channel per thread, serial over 64 pixels
    {
        int c = tid, e = tid & 31;
        const float* row = TS[c];
        float gs = 0.f, bs = 0.f;
        #pragma unroll 8
        for(int p=0;p<64;p++){
            float v = row[p ^ e];
            gs += v*wgt[p]; bs += v*wbt[p];
        }
        float* part = (float*)((char*)ws+OFF_PART);
        part[(size_t)blockIdx.x*512 + c]       = gs;
        part[(size_t)blockIdx.x*512 + 256 + c] = bs;
    }

    // pass C: fp16 feature rows for anchors in this tile
    int nh = nhit_s;
    half_t* fh = (half_t*)((char*)ws+OFF_FEATSH);
    int c = tid, e = tid & 31;
    for(int j=0;j<nh;j++){
        int p = hp[j], a = ha[j];
        fh[(size_t)a*C_ + c] = (half_t)(TS[c][p ^ e] * rn[p]);
    }
}

// K8b v3: split-i reduction of core partials, atomics into zeroed csum
__global__ void k_cored(void* ws){
    const float* part = (const float*)((char*)ws+OFF_PART);
    float* csum = (float*)((char*)ws+OFF_CORESUMG);   // [512] (G then B), memset 0
    int tid = threadIdx.x;
    int i0 = blockIdx.x*128;                          // 32 blocks x 128 i-values
    float s0=0.f, s1=0.f;
    for(int i=i0;i<i0+128;i++){
        s0 += part[(size_t)i*512 + tid];
        s1 += part[(size_t)i*512 + 256 + tid];
    }
    atomicAdd(csum+tid, s0);
    atomicAdd(csum+256+tid, s1);
}

// K9: core means + their norms
__global__ void k_coremean(void* ws){
    int cls = blockIdx.x, c = threadIdx.x;
    int* cnts = (int*)((char*)ws+OFF_CNTS);
    float* sum  = (float*)((char*)ws + (cls? OFF_CORESUMB : OFF_CORESUMG));
    float* mean = (float*)((char*)ws + (cls? OFF_COREMEANB: OFF_COREMEANG));
    int n = cnts[2+cls];
    float m = sum[c]/(float)n;
    mean[c] = m;
    float ss = waveReduceSum(m*m);
    __shared__ float wsum[4];
    int lane = c & 63, wid = c >> 6;
    if(lane==0) wsum[wid]=ss;
    __syncthreads();
    if(c==0) ((float*)((char*)ws+OFF_NPOS))[cls] = sqrtf(wsum[0]+wsum[1]+wsum[2]+wsum[3]);
}

// K10: fused anchor norm + pos logit from fp16 feats. One wave per anchor.
__global__ void k_anchor(void* ws){
    int* pi = (int*)((char*)ws+OFF_PLANI);
    int ntot = pi[10], ng = pi[8];
    int tid = threadIdx.x;
    int lane = tid & 63, wid = tid >> 6;
    int a = blockIdx.x*4 + wid;
    if(a >= ntot) return;
    int cls = (a < ng) ? 0 : 1;
    const float* mean = (const float*)((char*)ws + (cls? OFF_COREMEANB : OFF_COREMEANG));
    const half_t* feat = (const half_t*)((char*)ws+OFF_FEATSH) + (size_t)a*C_;
    half4 f4 = *(const half4*)&feat[lane*4];
    float fx = (float)f4[0], fy = (float)f4[1], fz = (float)f4[2], fw = (float)f4[3];
    float4 m = *(const float4*)&mean[lane*4];
    float ss = fx*fx + fy*fy + fz*fz + fw*fw;
    float dd = fx*m.x + fy*m.y + fz*m.z + fw*m.w;
    ss = waveReduceSum(ss); dd = waveReduceSum(dd);
    if(lane==0){
        float na = sqrtf(ss);
        float npos = ((float*)((char*)ws+OFF_NPOS))[cls];
        float den = fmaxf(na*npos, 1e-8f);
        ((float*)((char*)ws+OFF_NA))[a]   = na;
        ((float*)((char*)ws+OFF_RNA))[a]  = 1.0f/na;
        ((float*)((char*)ws+OFF_PLOG))[a] = (dd/den)*RTAU_;
    }
}

// ---------------------------------------------------------------------------
// K11 v7: LDS-staged double-buffered MFMA sim-GEMM, KSTEP=32 (unchanged).
// ---------------------------------------------------------------------------
#define KSTEP 32
#define NKS 8            // 256 / 32
#define NCHUNKS 15       // 8 A-chunks (1KB each) + 7 B-chunks
#define TILEB 15360      // bytes per buffer

__global__ __launch_bounds__(256, 4) void k_loss(void* ws){
    __shared__ __attribute__((aligned(16))) char S[2][TILEB];
    __shared__ float redsum[4];

    int at = blockIdx.x, f = blockIdx.y, l = blockIdx.z;
    int* pi = (int*)((char*)ws+OFF_PLANI);
    int ng = pi[8], nb = pi[9], ntot = pi[10], nbg = pi[11];
    int n_a = l ? (ntot-nbg) : nbg;
    int nfull = n_a/100, rem = n_a%100;
    int nch = nfull + (rem?1:0);
    if(f >= nch) return;
    int cs = (f < nfull) ? 100 : rem;
    int a0b = at*128;
    if(a0b >= n_a) return;
    int abase   = l ? nbg : 0;
    int negbase = l ? nbg : 0;
    const char* fhB      = (const char*)((char*)ws+OFF_FEATSH);
    const float* rnaArr  = (const float*)((char*)ws+OFF_RNA);
    const float* plogArr = (const float*)((char*)ws+OFF_PLOG);

    int tid = threadIdx.x;
    int wv = tid >> 6, lane = tid & 63;
    int qd = lane >> 4, ln = lane & 15;
    int a0 = a0b + wv*32;

    // per-lane rnn for the 7 neg col-tiles (epilogue only)
    float rnn[7];
    #pragma unroll
    for(int t=0;t<7;t++){
        int k = 16*t + ln;
        float rn = 1.0f;
        if(k < cs){
            int i = negbase + f*100 + k;
            int fi = (i < nb) ? (ng + i) : (i - nb);
            rn = rnaArr[fi];
        }
        rnn[t] = rn;
    }

    // precompute this wave's staging chunk sources (static-indexed, stays in regs)
    const char* gsrc[4];
    int subrow = lane >> 2;          // row within chunk [0,16)
    int colb   = (lane & 3) * 16;    // byte column within 64B row
    #pragma unroll
    for(int j=0;j<4;j++){
        int ch = wv + 4*j;
        gsrc[j] = fhB;
        if(ch < NCHUNKS){
            if(ch < 8){
                int r = ch*16 + subrow;
                int ar = a0b + r; if(ar >= n_a) ar = a0b;
                gsrc[j] = fhB + (size_t)(abase + ar)*512 + colb;
            } else {
                int rb = (ch-8)*16 + subrow;
                int kk = (rb < cs) ? rb : 0;
                int i = negbase + f*100 + kk;
                int fi = (i < nb) ? (ng + i) : (i - nb);
                gsrc[j] = fhB + (size_t)fi*512 + colb;
            }
        }
    }

    f32x4 acc[2][7];
    #pragma unroll
    for(int i=0;i<2;i++)
        #pragma unroll
        for(int t=0;t<7;t++) acc[i][t] = (f32x4){0.f,0.f,0.f,0.f};

    // prologue: stage K-step 0 into buffer 0
    #pragma unroll
    for(int j=0;j<4;j++){
        int ch = wv + 4*j;
        if(ch < NCHUNKS) gl_lds16(gsrc[j], (char*)S[0] + (ch<<10));
    }
    __syncthreads();

    int buf = 0;
    #pragma unroll 1
    for(int ks=0; ks<NKS; ks++){
        if(ks < NKS-1){
            #pragma unroll
            for(int j=0;j<4;j++){
                int ch = wv + 4*j;
                if(ch < NCHUNKS)
                    gl_lds16(gsrc[j] + (ks+1)*64, (char*)S[buf^1] + (ch<<10));
            }
        }
        const char* Ab = (const char*)S[buf];
        const char* Bb = (const char*)S[buf] + 8192;
        half8 af0 = *(const half8*)(Ab + (wv*32 + ln)*64 + qd*16);
        half8 af1 = *(const half8*)(Ab + (wv*32 + 16 + ln)*64 + qd*16);
        #pragma unroll
        for(int t=0;t<7;t++){
            half8 bf = *(const half8*)(Bb + (16*t + ln)*64 + qd*16);
            acc[0][t] = __builtin_amdgcn_mfma_f32_16x16x32_f16(af0, bf, acc[0][t], 0,0,0);
            acc[1][t] = __builtin_amdgcn_mfma_f32_16x16x32_f16(af1, bf, acc[1][t], 0,0,0);
        }
        __syncthreads();
        buf ^= 1;
    }

    // epilogue: per-lane exp-sums over its 7 n-cols, 16-lane quad reduce
    float myval = 0.f;
    #pragma unroll
    for(int ta=0; ta<2; ta++){
        #pragma unroll
        for(int r=0;r<4;r++){
            int a = a0 + 16*ta + 4*qd + r;
            float ra = (a < n_a) ? rnaArr[abase+a]*RTAU_ : 0.f;
            float s = 0.f;
            #pragma unroll
            for(int tn=0;tn<7;tn++){
                if(16*tn + ln < cs)
                    s += __expf(acc[ta][tn][r] * ra * rnn[tn]);
            }
            if(a >= n_a) s = 0.f;
            #pragma unroll
            for(int off=8; off; off>>=1) s += __shfl_down(s, off, 64);
            if(ln == 0 && a < n_a){
                float plog = plogArr[abase+a];
                myval += __logf(s + __expf(plog)) - plog;
            }
        }
    }
    myval = waveReduceSum(myval);
    if(lane==0) redsum[wv] = myval;
    __syncthreads();
    if(tid==0)
        atomicAdd((float*)((char*)ws+OFF_CHUNKSUM) + l*NCHUNK_MAX + f,
                  redsum[0]+redsum[1]+redsum[2]+redsum[3]);
}

// K12: final scalar
__global__ void k_final(void* ws, float* out){
    int* pi = (int*)((char*)ws+OFF_PLANI);
    int ntot = pi[10], nbg = pi[11];
    float* csum = (float*)((char*)ws+OFF_CHUNKSUM);
    float total = 0.f;
    for(int l=0;l<2;l++){
        int n_a = l ? (ntot-nbg) : nbg;
        int nfull = n_a/100, rem = n_a%100;
        int nch = nfull + (rem?1:0);
        float s = 0.f;
        for(int f=0; f<nch; f++) s += csum[l*NCHUNK_MAX+f]/(float)n_a;
        total += s/(float)nch;
    }
    *out = total;
}

extern "C" void kernel_launch(void* const* d_in, const int* in_sizes, int n_in,
                              void* d_out, int out_size, void* d_ws, size_t ws_size,
                              hipStream_t stream){
    const float* x      = (const float*)d_in[0];   // (1,256,512,512)
    const float* logits = (const float*)d_in[1];   // (1,2,512,512)
    const int*   seg    = (const int*)d_in[2];     // (1,512,512)
    float* out = (float*)d_out;

    hipMemsetAsync(d_ws, 0, ZERO_BYTES, stream);
    k_conf<<<256,256,0,stream>>>(logits, seg, d_ws);
    k_plan1<<<1,1,0,stream>>>(d_ws);
    k_poolcount<<<1024,256,0,stream>>>(logits, seg, d_ws);
    k_scan<<<4,256,0,stream>>>(d_ws);
    k_plan2<<<1,1,0,stream>>>(d_ws);
    k_fill<<<1024,256,0,stream>>>(logits, seg, d_ws);
    k_prep<<<PREPB,256,0,stream>>>(x, logits, seg, d_ws);
    k_cored<<<32,256,0,stream>>>(d_ws);
    k_coremean<<<2,256,0,stream>>>(d_ws);
    k_anchor<<<2048,256,0,stream>>>(d_ws);
    dim3 g(32, NCHUNK_MAX, 2);
    k_loss<<<g,256,0,stream>>>(d_ws);
    k_final<<<1,1,0,stream>>>(d_ws, out);
}